// Round 1
// baseline (1414.557 us; speedup 1.0000x reference)
//
#include <hip/hip_runtime.h>
#include <math.h>

// Problem constants (PicanetL): x (4,256,56,56) f32; W1 (128,256,7,7); b1 (128);
// W2 (49,128,1,1); b2 (49). dilation=2, pad=6 -> shape preserving.
#define B_   4
#define C_   256
#define H_   56
#define W_   56
#define HW_  3136
#define OC1  128
#define NT   49

// ---------------------------------------------------------------------------
// Kernel 0: transpose W1 [oc][c*49+t] -> wT [(c*49+t)][oc] so conv1 weight
// reads are wave-uniform (scalar s_load_dwordx4) with oc derived from blockIdx.
// ---------------------------------------------------------------------------
__global__ __launch_bounds__(256) void wt_kernel(const float* __restrict__ W1,
                                                 float* __restrict__ wT)
{
    int idx = blockIdx.x * 256 + threadIdx.x;   // < 128*12544 = 1,605,632
    int oc = idx & 127;
    int ct = idx >> 7;                          // c*49 + tap
    wT[idx] = W1[oc * (C_ * NT) + ct];
}

// ---------------------------------------------------------------------------
// Kernel 1: conv1 (7x7, dil 2, pad 6) + b1 -> k [B][128][HW]
// block = 256 threads = 4 waves; each wave owns one output row h (wave-uniform
// row-bounds branch), lane = w (0..63, active < 56). 8 ocs per thread.
// ---------------------------------------------------------------------------
__global__ __launch_bounds__(256) void conv1_kernel(const float* __restrict__ x,
                                                    const float* __restrict__ wT,
                                                    const float* __restrict__ b1,
                                                    float* __restrict__ k)
{
    int tid = threadIdx.x;
    int w   = tid & 63;
    int ty  = tid >> 6;                 // 0..3
    int h   = blockIdx.x * 4 + ty;      // 0..55
    int oc0 = blockIdx.y * 8;           // 0..120, scalar (blockIdx only)
    int b   = blockIdx.z;

    const float* xb = x + (size_t)b * C_ * HW_;
    float acc[8] = {0.f,0.f,0.f,0.f,0.f,0.f,0.f,0.f};

    for (int i = 0; i < 7; ++i) {
        int ih = h + 2 * i - 6;
        if (ih < 0 || ih >= H_) continue;       // wave-uniform branch
        for (int j = 0; j < 7; ++j) {
            int iw = w + 2 * j - 6;
            bool v  = (iw >= 0) && (iw < W_);
            float m = v ? 1.0f : 0.0f;          // mask-mul: always in-bounds load
            const float* xr = xb + ih * W_ + (v ? iw : 0);
            const float* wr = wT + (size_t)(i * 7 + j) * OC1 + oc0;  // uniform
            #pragma unroll 4
            for (int c = 0; c < C_; ++c) {
                float xv = m * xr[(size_t)c * HW_];
                const float4 w0 = *(const float4*)(wr + (size_t)c * NT * OC1);
                const float4 w1 = *(const float4*)(wr + (size_t)c * NT * OC1 + 4);
                acc[0] += xv * w0.x; acc[1] += xv * w0.y;
                acc[2] += xv * w0.z; acc[3] += xv * w0.w;
                acc[4] += xv * w1.x; acc[5] += xv * w1.y;
                acc[6] += xv * w1.z; acc[7] += xv * w1.w;
            }
        }
    }
    if (w < W_) {
        size_t o = ((size_t)(b * OC1 + oc0)) * HW_ + h * W_ + w;
        #pragma unroll
        for (int q = 0; q < 8; ++q)
            k[o + (size_t)q * HW_] = acc[q] + b1[oc0 + q];
    }
}

// ---------------------------------------------------------------------------
// Kernel 2: 1x1 conv (128->49) + b2 + softmax over the 49 -> attn [B][49][HW]
// One wave per pixel; lane l < 49 owns one logit. W2 transposed into LDS so
// lane reads are consecutive (<=2-way bank aliasing = free).
// ---------------------------------------------------------------------------
__global__ __launch_bounds__(256) void attn_kernel(const float* __restrict__ kin,
                                                   const float* __restrict__ W2,
                                                   const float* __restrict__ b2,
                                                   float* __restrict__ attn)
{
    __shared__ float sW2[128 * 49];
    int tid = threadIdx.x;
    for (int idx = tid; idx < 128 * 49; idx += 256) {
        int c = idx / 49, l = idx - c * 49;
        sW2[idx] = W2[l * 128 + c];
    }
    __syncthreads();

    int wid  = tid >> 6;
    int lane = tid & 63;
    int pix  = blockIdx.x * 4 + wid;       // < 12544
    int b    = pix / HW_;
    int hw   = pix - b * HW_;
    int l    = (lane < 49) ? lane : 0;

    const float* kb = kin + (size_t)b * OC1 * HW_ + hw;
    float acc = b2[l];
    #pragma unroll 8
    for (int c = 0; c < 128; ++c)
        acc += kb[(size_t)c * HW_] * sW2[c * 49 + l];

    float logit = (lane < 49) ? acc : -INFINITY;
    float mx = logit;
    for (int s = 32; s > 0; s >>= 1) mx = fmaxf(mx, __shfl_xor(mx, s, 64));
    float e = (lane < 49) ? __expf(logit - mx) : 0.0f;
    float sum = e;
    for (int s = 32; s > 0; s >>= 1) sum += __shfl_xor(sum, s, 64);
    if (lane < 49)
        attn[((size_t)b * NT + lane) * HW_ + hw] = e / sum;
}

// ---------------------------------------------------------------------------
// Kernel 3: out[b,c,h,w] = sum_{i,j} attn[b,ij,h,w] * x[b,c,h+2i-6,w+2j-6]
// Thread per output element; masked taps via clamp+mask-mul (no OOB).
// ---------------------------------------------------------------------------
__global__ __launch_bounds__(256) void out_kernel(const float* __restrict__ x,
                                                  const float* __restrict__ attn,
                                                  float* __restrict__ out)
{
    int idx = blockIdx.x * 256 + threadIdx.x;   // < 4*256*3136 = 3,211,264
    int w  = idx % 56;
    int t  = idx / 56;
    int h  = t % 56;
    int t2 = t / 56;
    int c  = t2 & 255;
    int b  = t2 >> 8;

    const float* xb = x + (size_t)(b * C_ + c) * HW_;
    const float* ab = attn + (size_t)b * NT * HW_ + h * W_ + w;

    float acc = 0.f;
    #pragma unroll
    for (int i = 0; i < 7; ++i) {
        int ih = h + 2 * i - 6;
        bool hv = (ih >= 0) && (ih < H_);
        #pragma unroll
        for (int j = 0; j < 7; ++j) {
            int iw = w + 2 * j - 6;
            bool v  = hv && (iw >= 0) && (iw < W_);
            float m = v ? 1.0f : 0.0f;
            int off = v ? (ih * W_ + iw) : 0;
            acc += (m * xb[off]) * ab[(size_t)(i * 7 + j) * HW_];
        }
    }
    out[idx] = acc;
}

// ---------------------------------------------------------------------------
extern "C" void kernel_launch(void* const* d_in, const int* in_sizes, int n_in,
                              void* d_out, int out_size, void* d_ws, size_t ws_size,
                              hipStream_t stream)
{
    const float* x  = (const float*)d_in[0];
    const float* W1 = (const float*)d_in[1];
    const float* b1 = (const float*)d_in[2];
    const float* W2 = (const float*)d_in[3];
    const float* b2 = (const float*)d_in[4];
    float* out = (float*)d_out;

    // ws layout (floats): wT | k | attn  => ~14.6 MB total
    float* wT   = (float*)d_ws;          // 1,605,632 floats
    float* kbuf = wT + 1605632;          // 1,605,632 floats
    float* attn = kbuf + 1605632;        //   614,656 floats

    wt_kernel  <<<6272, 256, 0, stream>>>(W1, wT);
    conv1_kernel<<<dim3(14, 16, 4), 256, 0, stream>>>(x, wT, b1, kbuf);
    attn_kernel<<<3136, 256, 0, stream>>>(kbuf, W2, b2, attn);
    out_kernel <<<12544, 256, 0, stream>>>(x, attn, out);
}

// Round 3
// 477.725 us; speedup vs baseline: 2.9610x; 2.9610x over previous
//
#include <hip/hip_runtime.h>
#include <hip/hip_bf16.h>
#include <math.h>

#define B_   4
#define C_   256
#define H_   56
#define W_   56
#define HW_  3136
#define OC1  128
#define NT   49
#define HP_  68          // 56 + 2*6 padded
#define M_TOT 12544      // B_*HW_

typedef __attribute__((ext_vector_type(8))) short bf16x8;
typedef __attribute__((ext_vector_type(4))) float f32x4;

// ===========================================================================
// FAST PATH (needs ~60.1 MB ws): bf16 MFMA implicit GEMM for conv1
// ===========================================================================

// Pack x (f32 NCHW) -> xp bf16 [b][hp 68][wp 68][c 256], zero borders.
__global__ __launch_bounds__(256) void xpack_kernel(const float* __restrict__ x,
                                                    __hip_bfloat16* __restrict__ xp)
{
    int idx = blockIdx.x * 256 + threadIdx.x;      // < 4*68*68*256 = 4,734,976
    int c  = idx & 255;
    int p  = idx >> 8;
    int wp = p % HP_;
    int p2 = p / HP_;
    int hp = p2 % HP_;
    int b  = p2 / HP_;
    int h = hp - 6, w = wp - 6;
    float v = 0.0f;
    if (h >= 0 && h < H_ && w >= 0 && w < W_)
        v = x[((size_t)(b * C_ + c)) * HW_ + h * W_ + w];
    xp[idx] = __float2bfloat16(v);
}

// Pack W1 -> wTb2 bf16 fragment order: [tap49][cc8][ntile8][lane64][j8]
// lane: n = ntile*16 + (lane&15); k(c) = cc*32 + (lane>>4)*8 + j
__global__ __launch_bounds__(256) void wpack_kernel(const float* __restrict__ W1,
                                                    __hip_bfloat16* __restrict__ wTb2)
{
    int idx = blockIdx.x * 256 + threadIdx.x;      // < 49*8*8*64*8 = 1,605,632
    int j8    = idx & 7;
    int l     = (idx >> 3) & 63;
    int ntile = (idx >> 9) & 7;
    int cc    = (idx >> 12) & 7;
    int tap   = idx >> 15;                          // 0..48
    int n = ntile * 16 + (l & 15);
    int c = cc * 32 + (l >> 4) * 8 + j8;
    wTb2[idx] = __float2bfloat16(W1[((size_t)n * C_ + c) * NT + tap]);
}

// conv1 implicit GEMM: grid (98 m-blocks, 7 tap-rows). Block 256 thr = 4 waves
// (2x2). Wave tile M64xN64 = 4x4 tiles of 16x16x32. No LDS, no barriers.
// kpart[i][m][n] = sum_{j,c} xp[pix_m + (2i,2j)][c] * W1[n][c][i*7+j]
__global__ __launch_bounds__(256) void conv1_mfma(const __hip_bfloat16* __restrict__ xp,
                                                  const __hip_bfloat16* __restrict__ wTb2,
                                                  float* __restrict__ kpart)
{
    const int m0   = blockIdx.x * 128;
    const int i    = blockIdx.y;          // tap row 0..6
    const int tid  = threadIdx.x;
    const int lane = tid & 63;
    const int wid  = tid >> 6;
    const int waveM = wid >> 1, waveN = wid & 1;
    const int quad = lane >> 4, l16 = lane & 15;

    const short* xps = (const short*)xp;
    const short* wbs = (const short*)wTb2;

    // Per-lane A base (element offsets into xps) for 4 m-tiles.
    long abase[4];
    #pragma unroll
    for (int mt = 0; mt < 4; ++mt) {
        int m = m0 + waveM * 64 + mt * 16 + l16;
        int b = m / HW_; int hw = m - b * HW_;
        int h = hw / W_; int w = hw - h * W_;
        abase[mt] = ((long)(b * HP_ + (h + 2 * i)) * HP_ + w) * 256 + quad * 8;
    }

    f32x4 acc[4][4];
    #pragma unroll
    for (int a = 0; a < 4; ++a)
        #pragma unroll
        for (int b2 = 0; b2 < 4; ++b2) acc[a][b2] = (f32x4){0.f, 0.f, 0.f, 0.f};

    const long bwave = (long)(waveN * 4) * 512 + lane * 8;

    for (int j = 0; j < 7; ++j) {
        const long aoffj = (long)j * 512;                  // += 2 cols * 256 c
        const long boffj = (long)(i * 7 + j) * 32768;      // tap*8cc*8nt*512
        #pragma unroll
        for (int cc = 0; cc < 8; ++cc) {
            bf16x8 af[4], bfr[4];
            #pragma unroll
            for (int mt = 0; mt < 4; ++mt)
                af[mt] = *(const bf16x8*)(xps + abase[mt] + aoffj + cc * 32);  // FIX: 32 shorts per K=32 channel block (was cc*64)
            #pragma unroll
            for (int nt = 0; nt < 4; ++nt)
                bfr[nt] = *(const bf16x8*)(wbs + boffj + (long)cc * 4096 + (long)nt * 512 + bwave);
            #pragma unroll
            for (int mt = 0; mt < 4; ++mt)
                #pragma unroll
                for (int nt = 0; nt < 4; ++nt)
                    acc[mt][nt] = __builtin_amdgcn_mfma_f32_16x16x32_bf16(
                        af[mt], bfr[nt], acc[mt][nt], 0, 0, 0);
        }
    }

    // Store: C/D layout col(n)=lane&15, row(m)=quad*4+reg
    #pragma unroll
    for (int mt = 0; mt < 4; ++mt) {
        int mrow = m0 + waveM * 64 + mt * 16 + quad * 4;
        #pragma unroll
        for (int nt = 0; nt < 4; ++nt) {
            int n = waveN * 64 + nt * 16 + l16;
            float* dst = kpart + ((long)i * M_TOT + mrow) * OC1 + n;
            #pragma unroll
            for (int r = 0; r < 4; ++r)
                dst[(long)r * OC1] = acc[mt][nt][r];
        }
    }
}

// conv2 (1x1,128->49) + b2 + softmax, folding the 7 kpart partials + b1.
// One wave per pixel; lane l<49 owns one logit.
__global__ __launch_bounds__(256) void attn_kernel2(const float* __restrict__ kpart,
                                                    const float* __restrict__ b1,
                                                    const float* __restrict__ W2,
                                                    const float* __restrict__ b2,
                                                    float* __restrict__ attn)
{
    __shared__ float sW2[128 * 49];
    int tid = threadIdx.x;
    for (int idx = tid; idx < 128 * 49; idx += 256) {
        int c = idx / 49, l = idx - c * 49;
        sW2[idx] = W2[l * 128 + c];
    }
    __syncthreads();

    int wid  = tid >> 6;
    int lane = tid & 63;
    int pix  = blockIdx.x * 4 + wid;       // < 12544
    int b    = pix / HW_;
    int hw   = pix - b * HW_;
    int l    = (lane < 49) ? lane : 0;

    const float* kp = kpart + (size_t)pix * OC1;
    float acc = b2[l];
    for (int c = 0; c < 128; c += 4) {
        float4 s = *(const float4*)(b1 + c);
        #pragma unroll
        for (int sp = 0; sp < 7; ++sp) {
            float4 p = *(const float4*)(kp + (size_t)sp * M_TOT * OC1 + c);
            s.x += p.x; s.y += p.y; s.z += p.z; s.w += p.w;
        }
        acc += s.x * sW2[(c + 0) * 49 + l] + s.y * sW2[(c + 1) * 49 + l]
             + s.z * sW2[(c + 2) * 49 + l] + s.w * sW2[(c + 3) * 49 + l];
    }

    float logit = (lane < 49) ? acc : -INFINITY;
    float mx = logit;
    for (int s = 32; s > 0; s >>= 1) mx = fmaxf(mx, __shfl_xor(mx, s, 64));
    float e = (lane < 49) ? __expf(logit - mx) : 0.0f;
    float sum = e;
    for (int s = 32; s > 0; s >>= 1) sum += __shfl_xor(sum, s, 64);
    if (lane < 49)
        attn[((size_t)b * NT + lane) * HW_ + hw] = e / sum;
}

// Weighted 49-tap gather (unchanged from R1).
__global__ __launch_bounds__(256) void out_kernel(const float* __restrict__ x,
                                                  const float* __restrict__ attn,
                                                  float* __restrict__ out)
{
    int idx = blockIdx.x * 256 + threadIdx.x;   // < 3,211,264
    int w  = idx % 56;
    int t  = idx / 56;
    int h  = t % 56;
    int t2 = t / 56;
    int c  = t2 & 255;
    int b  = t2 >> 8;

    const float* xb = x + (size_t)(b * C_ + c) * HW_;
    const float* ab = attn + (size_t)b * NT * HW_ + h * W_ + w;

    float acc = 0.f;
    #pragma unroll
    for (int i = 0; i < 7; ++i) {
        int ih = h + 2 * i - 6;
        bool hv = (ih >= 0) && (ih < H_);
        #pragma unroll
        for (int j = 0; j < 7; ++j) {
            int iw = w + 2 * j - 6;
            bool v  = hv && (iw >= 0) && (iw < W_);
            float m = v ? 1.0f : 0.0f;
            int off = v ? (ih * W_ + iw) : 0;
            acc += (m * xb[off]) * ab[(size_t)(i * 7 + j) * HW_];
        }
    }
    out[idx] = acc;
}

// ===========================================================================
// FALLBACK PATH (R1, proven): used only if ws_size < fast-path need
// ===========================================================================
__global__ __launch_bounds__(256) void wt_kernel(const float* __restrict__ W1,
                                                 float* __restrict__ wT)
{
    int idx = blockIdx.x * 256 + threadIdx.x;
    int oc = idx & 127;
    int ct = idx >> 7;
    wT[idx] = W1[oc * (C_ * NT) + ct];
}

__global__ __launch_bounds__(256) void conv1_kernel(const float* __restrict__ x,
                                                    const float* __restrict__ wT,
                                                    const float* __restrict__ b1,
                                                    float* __restrict__ k)
{
    int tid = threadIdx.x;
    int w   = tid & 63;
    int ty  = tid >> 6;
    int h   = blockIdx.x * 4 + ty;
    int oc0 = blockIdx.y * 8;
    int b   = blockIdx.z;

    const float* xb = x + (size_t)b * C_ * HW_;
    float acc[8] = {0.f,0.f,0.f,0.f,0.f,0.f,0.f,0.f};

    for (int i = 0; i < 7; ++i) {
        int ih = h + 2 * i - 6;
        if (ih < 0 || ih >= H_) continue;
        for (int j = 0; j < 7; ++j) {
            int iw = w + 2 * j - 6;
            bool v  = (iw >= 0) && (iw < W_);
            float m = v ? 1.0f : 0.0f;
            const float* xr = xb + ih * W_ + (v ? iw : 0);
            const float* wr = wT + (size_t)(i * 7 + j) * OC1 + oc0;
            #pragma unroll 4
            for (int c = 0; c < C_; ++c) {
                float xv = m * xr[(size_t)c * HW_];
                const float4 w0 = *(const float4*)(wr + (size_t)c * NT * OC1);
                const float4 w1 = *(const float4*)(wr + (size_t)c * NT * OC1 + 4);
                acc[0] += xv * w0.x; acc[1] += xv * w0.y;
                acc[2] += xv * w0.z; acc[3] += xv * w0.w;
                acc[4] += xv * w1.x; acc[5] += xv * w1.y;
                acc[6] += xv * w1.z; acc[7] += xv * w1.w;
            }
        }
    }
    if (w < W_) {
        size_t o = ((size_t)(b * OC1 + oc0)) * HW_ + h * W_ + w;
        #pragma unroll
        for (int q = 0; q < 8; ++q)
            k[o + (size_t)q * HW_] = acc[q] + b1[oc0 + q];
    }
}

__global__ __launch_bounds__(256) void attn_kernel(const float* __restrict__ kin,
                                                   const float* __restrict__ W2,
                                                   const float* __restrict__ b2,
                                                   float* __restrict__ attn)
{
    __shared__ float sW2[128 * 49];
    int tid = threadIdx.x;
    for (int idx = tid; idx < 128 * 49; idx += 256) {
        int c = idx / 49, l = idx - c * 49;
        sW2[idx] = W2[l * 128 + c];
    }
    __syncthreads();

    int wid  = tid >> 6;
    int lane = tid & 63;
    int pix  = blockIdx.x * 4 + wid;
    int b    = pix / HW_;
    int hw   = pix - b * HW_;
    int l    = (lane < 49) ? lane : 0;

    const float* kb = kin + (size_t)b * OC1 * HW_ + hw;
    float acc = b2[l];
    #pragma unroll 8
    for (int c = 0; c < 128; ++c)
        acc += kb[(size_t)c * HW_] * sW2[c * 49 + l];

    float logit = (lane < 49) ? acc : -INFINITY;
    float mx = logit;
    for (int s = 32; s > 0; s >>= 1) mx = fmaxf(mx, __shfl_xor(mx, s, 64));
    float e = (lane < 49) ? __expf(logit - mx) : 0.0f;
    float sum = e;
    for (int s = 32; s > 0; s >>= 1) sum += __shfl_xor(sum, s, 64);
    if (lane < 49)
        attn[((size_t)b * NT + lane) * HW_ + hw] = e / sum;
}

// ===========================================================================
extern "C" void kernel_launch(void* const* d_in, const int* in_sizes, int n_in,
                              void* d_out, int out_size, void* d_ws, size_t ws_size,
                              hipStream_t stream)
{
    const float* x  = (const float*)d_in[0];
    const float* W1 = (const float*)d_in[1];
    const float* b1 = (const float*)d_in[2];
    const float* W2 = (const float*)d_in[3];
    const float* b2 = (const float*)d_in[4];
    float* out = (float*)d_out;

    // fast-path ws layout (bytes):
    const size_t xp_b    = (size_t)B_ * HP_ * HP_ * 256 * 2;        //  9,469,952
    const size_t wtb_b   = (size_t)NT * 8 * 8 * 64 * 8 * 2;         //  3,211,264
    const size_t kpart_b = (size_t)7 * M_TOT * OC1 * 4;             // 44,957,696
    const size_t attn_b  = (size_t)B_ * NT * HW_ * 4;               //  2,458,624
    const size_t need = xp_b + wtb_b + kpart_b + attn_b;            // 60,097,536

    if (ws_size >= need) {
        char* base = (char*)d_ws;
        __hip_bfloat16* xp   = (__hip_bfloat16*)base;
        __hip_bfloat16* wTb2 = (__hip_bfloat16*)(base + xp_b);
        float* kpart = (float*)(base + xp_b + wtb_b);
        float* attn  = (float*)(base + xp_b + wtb_b + kpart_b);

        xpack_kernel<<<18496, 256, 0, stream>>>(x, xp);
        wpack_kernel<<<6272, 256, 0, stream>>>(W1, wTb2);
        conv1_mfma  <<<dim3(98, 7), 256, 0, stream>>>(xp, wTb2, kpart);
        attn_kernel2<<<3136, 256, 0, stream>>>(kpart, b1, W2, b2, attn);
        out_kernel  <<<12544, 256, 0, stream>>>(x, attn, out);
    } else {
        // R1 fallback (~14.6 MB)
        float* wT   = (float*)d_ws;
        float* kbuf = wT + 1605632;
        float* attn = kbuf + 1605632;
        wt_kernel   <<<6272, 256, 0, stream>>>(W1, wT);
        conv1_kernel<<<dim3(14, 16, 4), 256, 0, stream>>>(x, wT, b1, kbuf);
        attn_kernel <<<3136, 256, 0, stream>>>(kbuf, W2, b2, attn);
        out_kernel  <<<12544, 256, 0, stream>>>(x, attn, out);
    }
}

// Round 4
// 279.322 us; speedup vs baseline: 5.0643x; 1.7103x over previous
//
#include <hip/hip_runtime.h>
#include <hip/hip_bf16.h>
#include <math.h>

#define B_   4
#define C_   256
#define H_   56
#define W_   56
#define HW_  3136
#define OC1  128
#define NT   49
#define HP_  68          // 56 + 2*6 padded
#define M_TOT 12544      // B_*HW_

typedef __attribute__((ext_vector_type(8))) short bf16x8;
typedef __attribute__((ext_vector_type(4))) float f32x4;

// ===========================================================================
// FAST PATH: bf16 MFMA implicit GEMM for conv1, cc-blocked xp layout
// xp2 layout: [cc 8][b 4][hp 68][wp 68][ci 32] bf16
// ===========================================================================

// Pack x (f32 NCHW) -> xp2, zero borders. One block per (cc, b, hp).
__global__ __launch_bounds__(256) void xpack2_kernel(const float* __restrict__ x,
                                                     __hip_bfloat16* __restrict__ xp)
{
    __shared__ short tile[HP_ * 32];     // [wp][ci]
    int bid = blockIdx.x;                // < 8*4*68 = 2176
    int cc = bid / (B_ * HP_);
    int r  = bid - cc * (B_ * HP_);
    int b  = r / HP_;
    int hp = r - b * HP_;
    int h  = hp - 6;
    int tid = threadIdx.x;

    if (h < 0 || h >= H_) {
        for (int idx = tid; idx < HP_ * 32; idx += 256) tile[idx] = 0;
    } else {
        int ci = tid >> 3;               // 0..31
        int wg = tid & 7;                // 0..7
        const float* xr = x + ((size_t)(b * C_ + cc * 32 + ci) * H_ + h) * W_;
        #pragma unroll
        for (int k = 0; k < 7; ++k) {
            int w = wg + 8 * k;          // covers 0..55 exactly
            __hip_bfloat16 v = __float2bfloat16(xr[w]);
            tile[(w + 6) * 32 + ci] = *(short*)&v;
        }
        // zero left/right borders: wp in [0,6) and [62,68): 12*32 = 384 entries
        for (int idx = tid; idx < 384; idx += 256) {
            int wp = idx >> 5;           // 0..11
            int wz = (wp < 6) ? wp : (wp + 56);
            tile[wz * 32 + (idx & 31)] = 0;
        }
    }
    __syncthreads();
    // contiguous write: 68*32 = 2176 shorts = 272 x 16B
    short* outp = (short*)xp + ((size_t)((cc * B_ + b) * HP_ + hp) * HP_) * 32;
    for (int idx = tid; idx < 272; idx += 256)
        *(bf16x8*)(outp + idx * 8) = *(bf16x8*)(tile + idx * 8);
}

// Pack W1 -> wTb2 bf16 fragment order: [tap49][cc8][ntile8][lane64][j8]
// lane: n = ntile*16 + (lane&15); k(c) = cc*32 + (lane>>4)*8 + j   (validated R3)
__global__ __launch_bounds__(256) void wpack_kernel(const float* __restrict__ W1,
                                                    __hip_bfloat16* __restrict__ wTb2)
{
    int idx = blockIdx.x * 256 + threadIdx.x;      // < 49*8*8*64*8 = 1,605,632
    int j8    = idx & 7;
    int l     = (idx >> 3) & 63;
    int ntile = (idx >> 9) & 7;
    int cc    = (idx >> 12) & 7;
    int tap   = idx >> 15;                          // 0..48
    int n = ntile * 16 + (l & 15);
    int c = cc * 32 + (l >> 4) * 8 + j8;
    wTb2[idx] = __float2bfloat16(W1[((size_t)n * C_ + c) * NT + tap]);
}

// conv1 implicit GEMM. Grid = 728 (8 XCD slots x 91). XCD-swizzled so XCD g
// owns contiguous m-blocks [g*98/8, (g+1)*98/8) for all 7 tap-rows -> its xp
// slice (~1.4 MB) fits the 4 MB per-XCD L2. Loop order cc-outer/j-inner for
// L1 reuse of the 7 shifted A reads. MFMA/store logic identical to R3.
__global__ __launch_bounds__(256) void conv1_mfma2(const __hip_bfloat16* __restrict__ xp,
                                                   const __hip_bfloat16* __restrict__ wTb2,
                                                   float* __restrict__ kpart)
{
    const int bid = blockIdx.x;
    const int g   = bid & 7;              // presumed XCD (round-robin dispatch)
    const int kk  = bid >> 3;             // 0..90
    const int s   = (g * 98) >> 3;
    const int cnt = (((g + 1) * 98) >> 3) - s;   // 12 or 13
    const int i   = kk / cnt;             // tap row
    if (i >= 7) return;
    const int mblk = s + (kk - i * cnt);
    const int m0   = mblk * 128;

    const int tid  = threadIdx.x;
    const int lane = tid & 63;
    const int wid  = tid >> 6;
    const int waveM = wid >> 1, waveN = wid & 1;
    const int quad = lane >> 4, l16 = lane & 15;

    const short* xps = (const short*)xp;
    const short* wbs = (const short*)wTb2;
    const long CC_STRIDE = (long)B_ * HP_ * HP_ * 32;   // 591,872 elements

    // Per-lane A base (xp2 element offsets), cc/j added in-loop.
    long abase[4];
    #pragma unroll
    for (int mt = 0; mt < 4; ++mt) {
        int m = m0 + waveM * 64 + mt * 16 + l16;
        int b = m / HW_; int hw = m - b * HW_;
        int h = hw / W_; int w = hw - h * W_;
        abase[mt] = ((long)(b * HP_ + (h + 2 * i)) * HP_ + w) * 32 + quad * 8;
    }

    f32x4 acc[4][4];
    #pragma unroll
    for (int a = 0; a < 4; ++a)
        #pragma unroll
        for (int b2 = 0; b2 < 4; ++b2) acc[a][b2] = (f32x4){0.f, 0.f, 0.f, 0.f};

    const long bwave = (long)(waveN * 4) * 512 + lane * 8;

    #pragma unroll
    for (int cc = 0; cc < 8; ++cc) {
        const long aoffc = (long)cc * CC_STRIDE;
        const long boffc = (long)cc * 4096;
        for (int j = 0; j < 7; ++j) {
            const long aoffj = aoffc + (long)j * 64;            // wp += 2
            const long boffj = (long)(i * 7 + j) * 32768 + boffc;
            bf16x8 af[4], bfr[4];
            #pragma unroll
            for (int mt = 0; mt < 4; ++mt)
                af[mt] = *(const bf16x8*)(xps + abase[mt] + aoffj);
            #pragma unroll
            for (int nt = 0; nt < 4; ++nt)
                bfr[nt] = *(const bf16x8*)(wbs + boffj + (long)nt * 512 + bwave);
            #pragma unroll
            for (int mt = 0; mt < 4; ++mt)
                #pragma unroll
                for (int nt = 0; nt < 4; ++nt)
                    acc[mt][nt] = __builtin_amdgcn_mfma_f32_16x16x32_bf16(
                        af[mt], bfr[nt], acc[mt][nt], 0, 0, 0);
        }
    }

    // Store: C/D layout col(n)=lane&15, row(m)=quad*4+reg  (validated R3)
    #pragma unroll
    for (int mt = 0; mt < 4; ++mt) {
        int mrow = m0 + waveM * 64 + mt * 16 + quad * 4;
        #pragma unroll
        for (int nt = 0; nt < 4; ++nt) {
            int n = waveN * 64 + nt * 16 + l16;
            float* dst = kpart + ((long)i * M_TOT + mrow) * OC1 + n;
            #pragma unroll
            for (int r = 0; r < 4; ++r)
                dst[(long)r * OC1] = acc[mt][nt][r];
        }
    }
}

// conv2 + b2 + softmax, folding 7 kpart slices + b1. Block-cooperative:
// 32 pixels/block, lane-parallel coalesced loads (fixes R3's wave-uniform
// serial k-streaming). ksum LDS is [c][pix+pad] so phase-2 reads broadcast.
__global__ __launch_bounds__(256) void attn_kernel3(const float* __restrict__ kpart,
                                                    const float* __restrict__ b1,
                                                    const float* __restrict__ W2,
                                                    const float* __restrict__ b2,
                                                    float* __restrict__ attn)
{
    __shared__ float ksum[128 * 33];     // [c][pix], pad 33
    __shared__ float sW2[128 * 49];      // [c][l]
    __shared__ float sredA[32 * 8];
    __shared__ float sredB[32 * 8];

    int tid  = threadIdx.x;
    int pix0 = blockIdx.x * 32;

    for (int idx = tid; idx < 128 * 49; idx += 256) {
        int c = idx / 49, l = idx - c * 49;
        sW2[idx] = W2[l * 128 + c];
    }

    // phase 1: fold 7 partials + b1. thread -> (pix = tid>>3, cg = tid&7)
    int pix = tid >> 3, cg = tid & 7;
    {
        const float* kp = kpart + (size_t)(pix0 + pix) * OC1;
        #pragma unroll
        for (int q = 0; q < 4; ++q) {
            int c4 = cg * 16 + q * 4;
            float4 s = *(const float4*)(b1 + c4);
            #pragma unroll
            for (int sp = 0; sp < 7; ++sp) {
                float4 p = *(const float4*)(kp + (size_t)sp * M_TOT * OC1 + c4);
                s.x += p.x; s.y += p.y; s.z += p.z; s.w += p.w;
            }
            ksum[(c4 + 0) * 33 + pix] = s.x;
            ksum[(c4 + 1) * 33 + pix] = s.y;
            ksum[(c4 + 2) * 33 + pix] = s.z;
            ksum[(c4 + 3) * 33 + pix] = s.w;
        }
    }
    __syncthreads();

    // phase 2: logits. thread -> (pix, sub = tid&7), taps l = sub + 8k
    int sub = tid & 7;
    float lg[7];
    int ntaps = 0;
    float lmax = -INFINITY;
    for (int l = sub; l < 49; l += 8) {
        float acc = b2[l];
        #pragma unroll 8
        for (int c = 0; c < 128; ++c)
            acc += ksum[c * 33 + pix] * sW2[c * 49 + l];
        lg[ntaps++] = acc;
        lmax = fmaxf(lmax, acc);
    }
    sredA[pix * 8 + sub] = lmax;
    __syncthreads();

    float m = sredA[pix * 8 + 0];
    #pragma unroll
    for (int t = 1; t < 8; ++t) m = fmaxf(m, sredA[pix * 8 + t]);
    float es = 0.f;
    for (int t = 0; t < ntaps; ++t) { lg[t] = __expf(lg[t] - m); es += lg[t]; }
    sredB[pix * 8 + sub] = es;
    __syncthreads();

    float S = 0.f;
    #pragma unroll
    for (int t = 0; t < 8; ++t) S += sredB[pix * 8 + t];
    float rinv = 1.0f / S;

    int pg = pix0 + pix;
    int b  = pg / HW_;
    int hw = pg - b * HW_;
    int t = 0;
    for (int l = sub; l < 49; l += 8, ++t)
        attn[((size_t)b * NT + l) * HW_ + hw] = lg[t] * rinv;
}

// out[b,c,h,w] = sum_ij attn[b,ij,h,w] * x[b,c,h+2i-6,w+2j-6]
// Block per (b,h,c-quarter): attn row staged in LDS once (kills 256x re-read),
// lane = w, x row reads coalesced and L1-hot across the 7 j-shifts.
__global__ __launch_bounds__(256) void out_kernel2(const float* __restrict__ x,
                                                   const float* __restrict__ attn,
                                                   float* __restrict__ out)
{
    __shared__ float sA[NT * 56];        // [tap][w]
    int bh = blockIdx.x;                 // < 224
    int b  = bh / H_;
    int h  = bh - b * H_;
    int cq = blockIdx.y;                 // 0..3
    int tid = threadIdx.x;

    for (int idx = tid; idx < NT * 56; idx += 256) {
        int l = idx / 56, w = idx - l * 56;
        sA[idx] = attn[((size_t)b * NT + l) * HW_ + h * W_ + w];
    }
    __syncthreads();

    int wid  = tid >> 6;
    int lane = tid & 63;
    int w    = lane;
    bool active = (w < W_);
    int wc = active ? w : (W_ - 1);

    // per-j masks/offsets (lane-dependent, hoisted out of c-loop)
    float jm[7]; int joff[7];
    #pragma unroll
    for (int j = 0; j < 7; ++j) {
        int iw = w + 2 * j - 6;
        bool v = active && (iw >= 0) && (iw < W_);
        jm[j]   = v ? 1.0f : 0.0f;
        joff[j] = v ? iw : 0;
    }

    int cbase = cq * 64 + wid * 16;
    for (int k = 0; k < 16; ++k) {
        int c = cbase + k;
        const float* xc = x + (size_t)(b * C_ + c) * HW_;
        float acc = 0.f;
        #pragma unroll
        for (int i = 0; i < 7; ++i) {
            int ih = h + 2 * i - 6;
            if (ih < 0 || ih >= H_) continue;        // wave-uniform
            const float* xr = xc + ih * W_;
            #pragma unroll
            for (int j = 0; j < 7; ++j)
                acc += sA[(i * 7 + j) * 56 + wc] * (jm[j] * xr[joff[j]]);
        }
        if (active)
            out[((size_t)(b * C_ + c)) * HW_ + h * W_ + w] = acc;
    }
}

// ===========================================================================
// FALLBACK PATH (R1, proven): used only if ws_size < fast-path need
// ===========================================================================
__global__ __launch_bounds__(256) void wt_kernel(const float* __restrict__ W1,
                                                 float* __restrict__ wT)
{
    int idx = blockIdx.x * 256 + threadIdx.x;
    int oc = idx & 127;
    int ct = idx >> 7;
    wT[idx] = W1[oc * (C_ * NT) + ct];
}

__global__ __launch_bounds__(256) void conv1_kernel(const float* __restrict__ x,
                                                    const float* __restrict__ wT,
                                                    const float* __restrict__ b1,
                                                    float* __restrict__ k)
{
    int tid = threadIdx.x;
    int w   = tid & 63;
    int ty  = tid >> 6;
    int h   = blockIdx.x * 4 + ty;
    int oc0 = blockIdx.y * 8;
    int b   = blockIdx.z;

    const float* xb = x + (size_t)b * C_ * HW_;
    float acc[8] = {0.f,0.f,0.f,0.f,0.f,0.f,0.f,0.f};

    for (int i = 0; i < 7; ++i) {
        int ih = h + 2 * i - 6;
        if (ih < 0 || ih >= H_) continue;
        for (int j = 0; j < 7; ++j) {
            int iw = w + 2 * j - 6;
            bool v  = (iw >= 0) && (iw < W_);
            float m = v ? 1.0f : 0.0f;
            const float* xr = xb + ih * W_ + (v ? iw : 0);
            const float* wr = wT + (size_t)(i * 7 + j) * OC1 + oc0;
            #pragma unroll 4
            for (int c = 0; c < C_; ++c) {
                float xv = m * xr[(size_t)c * HW_];
                const float4 w0 = *(const float4*)(wr + (size_t)c * NT * OC1);
                const float4 w1 = *(const float4*)(wr + (size_t)c * NT * OC1 + 4);
                acc[0] += xv * w0.x; acc[1] += xv * w0.y;
                acc[2] += xv * w0.z; acc[3] += xv * w0.w;
                acc[4] += xv * w1.x; acc[5] += xv * w1.y;
                acc[6] += xv * w1.z; acc[7] += xv * w1.w;
            }
        }
    }
    if (w < W_) {
        size_t o = ((size_t)(b * OC1 + oc0)) * HW_ + h * W_ + w;
        #pragma unroll
        for (int q = 0; q < 8; ++q)
            k[o + (size_t)q * HW_] = acc[q] + b1[oc0 + q];
    }
}

__global__ __launch_bounds__(256) void attn_kernel(const float* __restrict__ kin,
                                                   const float* __restrict__ W2,
                                                   const float* __restrict__ b2,
                                                   float* __restrict__ attn)
{
    __shared__ float sW2[128 * 49];
    int tid = threadIdx.x;
    for (int idx = tid; idx < 128 * 49; idx += 256) {
        int c = idx / 49, l = idx - c * 49;
        sW2[idx] = W2[l * 128 + c];
    }
    __syncthreads();

    int wid  = tid >> 6;
    int lane = tid & 63;
    int pix  = blockIdx.x * 4 + wid;
    int b    = pix / HW_;
    int hw   = pix - b * HW_;
    int l    = (lane < 49) ? lane : 0;

    const float* kb = kin + (size_t)b * OC1 * HW_ + hw;
    float acc = b2[l];
    #pragma unroll 8
    for (int c = 0; c < 128; ++c)
        acc += kb[(size_t)c * HW_] * sW2[c * 49 + l];

    float logit = (lane < 49) ? acc : -INFINITY;
    float mx = logit;
    for (int s = 32; s > 0; s >>= 1) mx = fmaxf(mx, __shfl_xor(mx, s, 64));
    float e = (lane < 49) ? __expf(logit - mx) : 0.0f;
    float sum = e;
    for (int s = 32; s > 0; s >>= 1) sum += __shfl_xor(sum, s, 64);
    if (lane < 49)
        attn[((size_t)b * NT + lane) * HW_ + hw] = e / sum;
}

__global__ __launch_bounds__(256) void out_kernel(const float* __restrict__ x,
                                                  const float* __restrict__ attn,
                                                  float* __restrict__ out)
{
    int idx = blockIdx.x * 256 + threadIdx.x;
    int w  = idx % 56;
    int t  = idx / 56;
    int h  = t % 56;
    int t2 = t / 56;
    int c  = t2 & 255;
    int b  = t2 >> 8;

    const float* xb = x + (size_t)(b * C_ + c) * HW_;
    const float* ab = attn + (size_t)b * NT * HW_ + h * W_ + w;

    float acc = 0.f;
    #pragma unroll
    for (int i = 0; i < 7; ++i) {
        int ih = h + 2 * i - 6;
        bool hv = (ih >= 0) && (ih < H_);
        #pragma unroll
        for (int j = 0; j < 7; ++j) {
            int iw = w + 2 * j - 6;
            bool v  = hv && (iw >= 0) && (iw < W_);
            float m = v ? 1.0f : 0.0f;
            int off = v ? (ih * W_ + iw) : 0;
            acc += (m * xb[off]) * ab[(size_t)(i * 7 + j) * HW_];
        }
    }
    out[idx] = acc;
}

// ===========================================================================
extern "C" void kernel_launch(void* const* d_in, const int* in_sizes, int n_in,
                              void* d_out, int out_size, void* d_ws, size_t ws_size,
                              hipStream_t stream)
{
    const float* x  = (const float*)d_in[0];
    const float* W1 = (const float*)d_in[1];
    const float* b1 = (const float*)d_in[2];
    const float* W2 = (const float*)d_in[3];
    const float* b2 = (const float*)d_in[4];
    float* out = (float*)d_out;

    const size_t xp_b    = (size_t)B_ * HP_ * HP_ * 256 * 2;        //  9,469,952
    const size_t wtb_b   = (size_t)NT * 8 * 8 * 64 * 8 * 2;         //  3,211,264
    const size_t kpart_b = (size_t)7 * M_TOT * OC1 * 4;             // 44,957,696
    const size_t attn_b  = (size_t)B_ * NT * HW_ * 4;               //  2,458,624
    const size_t need = xp_b + wtb_b + kpart_b + attn_b;            // 60,097,536

    if (ws_size >= need) {
        char* base = (char*)d_ws;
        __hip_bfloat16* xp   = (__hip_bfloat16*)base;
        __hip_bfloat16* wTb2 = (__hip_bfloat16*)(base + xp_b);
        float* kpart = (float*)(base + xp_b + wtb_b);
        float* attn  = (float*)(base + xp_b + wtb_b + kpart_b);

        xpack2_kernel<<<2176, 256, 0, stream>>>(x, xp);
        wpack_kernel <<<6272, 256, 0, stream>>>(W1, wTb2);
        conv1_mfma2  <<<728, 256, 0, stream>>>(xp, wTb2, kpart);
        attn_kernel3 <<<392, 256, 0, stream>>>(kpart, b1, W2, b2, attn);
        out_kernel2  <<<dim3(224, 4), 256, 0, stream>>>(x, attn, out);
    } else {
        // R1 fallback (~14.6 MB)
        float* wT   = (float*)d_ws;
        float* kbuf = wT + 1605632;
        float* attn = kbuf + 1605632;
        wt_kernel   <<<6272, 256, 0, stream>>>(W1, wT);
        conv1_kernel<<<dim3(14, 16, 4), 256, 0, stream>>>(x, wT, b1, kbuf);
        attn_kernel <<<3136, 256, 0, stream>>>(kbuf, W2, b2, attn);
        out_kernel  <<<12544, 256, 0, stream>>>(x, attn, out);
    }
}

// Round 5
// 222.067 us; speedup vs baseline: 6.3700x; 1.2578x over previous
//
#include <hip/hip_runtime.h>
#include <hip/hip_bf16.h>
#include <math.h>

#define B_   4
#define C_   256
#define H_   56
#define W_   56
#define HW_  3136
#define OC1  128
#define NT   49
#define HP_  68          // 56 + 2*6 padded
#define M_TOT 12544      // B_*HW_

typedef __attribute__((ext_vector_type(8))) short bf16x8;
typedef __attribute__((ext_vector_type(4))) float f32x4;

// ===========================================================================
// FAST PATH: bf16 MFMA implicit GEMM for conv1, cc-blocked xp layout
// xp2 layout: [cc 8][b 4][hp 68][wp 68][ci 32] bf16
// ===========================================================================

// Pack x (f32 NCHW) -> xp2, zero borders. One block per (cc, b, hp).
__global__ __launch_bounds__(256) void xpack2_kernel(const float* __restrict__ x,
                                                     __hip_bfloat16* __restrict__ xp)
{
    __shared__ short tile[HP_ * 32];     // [wp][ci]
    int bid = blockIdx.x;                // < 8*4*68 = 2176
    int cc = bid / (B_ * HP_);
    int r  = bid - cc * (B_ * HP_);
    int b  = r / HP_;
    int hp = r - b * HP_;
    int h  = hp - 6;
    int tid = threadIdx.x;

    if (h < 0 || h >= H_) {
        for (int idx = tid; idx < HP_ * 32; idx += 256) tile[idx] = 0;
    } else {
        int ci = tid >> 3;               // 0..31
        int wg = tid & 7;                // 0..7
        const float* xr = x + ((size_t)(b * C_ + cc * 32 + ci) * H_ + h) * W_;
        #pragma unroll
        for (int k = 0; k < 7; ++k) {
            int w = wg + 8 * k;          // covers 0..55 exactly
            __hip_bfloat16 v = __float2bfloat16(xr[w]);
            tile[(w + 6) * 32 + ci] = *(short*)&v;
        }
        // zero left/right borders: wp in [0,6) and [62,68): 12*32 = 384 entries
        for (int idx = tid; idx < 384; idx += 256) {
            int wp = idx >> 5;           // 0..11
            int wz = (wp < 6) ? wp : (wp + 56);
            tile[wz * 32 + (idx & 31)] = 0;
        }
    }
    __syncthreads();
    // contiguous write: 68*32 = 2176 shorts = 272 x 16B
    short* outp = (short*)xp + ((size_t)((cc * B_ + b) * HP_ + hp) * HP_) * 32;
    for (int idx = tid; idx < 272; idx += 256)
        *(bf16x8*)(outp + idx * 8) = *(bf16x8*)(tile + idx * 8);
}

// Pack W1 -> wTb2 bf16 fragment order: [tap49][cc8][ntile8][lane64][j8]
// lane: n = ntile*16 + (lane&15); k(c) = cc*32 + (lane>>4)*8 + j   (validated R3)
__global__ __launch_bounds__(256) void wpack_kernel(const float* __restrict__ W1,
                                                    __hip_bfloat16* __restrict__ wTb2)
{
    int idx = blockIdx.x * 256 + threadIdx.x;      // < 49*8*8*64*8 = 1,605,632
    int j8    = idx & 7;
    int l     = (idx >> 3) & 63;
    int ntile = (idx >> 9) & 7;
    int cc    = (idx >> 12) & 7;
    int tap   = idx >> 15;                          // 0..48
    int n = ntile * 16 + (l & 15);
    int c = cc * 32 + (l >> 4) * 8 + j8;
    wTb2[idx] = __float2bfloat16(W1[((size_t)n * C_ + c) * NT + tap]);
}

// conv1 implicit GEMM (validated R4). XCD-swizzled; cc-outer/j-inner.
__global__ __launch_bounds__(256) void conv1_mfma2(const __hip_bfloat16* __restrict__ xp,
                                                   const __hip_bfloat16* __restrict__ wTb2,
                                                   float* __restrict__ kpart)
{
    const int bid = blockIdx.x;
    const int g   = bid & 7;              // presumed XCD (round-robin dispatch)
    const int kk  = bid >> 3;             // 0..90
    const int s   = (g * 98) >> 3;
    const int cnt = (((g + 1) * 98) >> 3) - s;   // 12 or 13
    const int i   = kk / cnt;             // tap row
    if (i >= 7) return;
    const int mblk = s + (kk - i * cnt);
    const int m0   = mblk * 128;

    const int tid  = threadIdx.x;
    const int lane = tid & 63;
    const int wid  = tid >> 6;
    const int waveM = wid >> 1, waveN = wid & 1;
    const int quad = lane >> 4, l16 = lane & 15;

    const short* xps = (const short*)xp;
    const short* wbs = (const short*)wTb2;
    const long CC_STRIDE = (long)B_ * HP_ * HP_ * 32;   // 591,872 elements

    long abase[4];
    #pragma unroll
    for (int mt = 0; mt < 4; ++mt) {
        int m = m0 + waveM * 64 + mt * 16 + l16;
        int b = m / HW_; int hw = m - b * HW_;
        int h = hw / W_; int w = hw - h * W_;
        abase[mt] = ((long)(b * HP_ + (h + 2 * i)) * HP_ + w) * 32 + quad * 8;
    }

    f32x4 acc[4][4];
    #pragma unroll
    for (int a = 0; a < 4; ++a)
        #pragma unroll
        for (int b2 = 0; b2 < 4; ++b2) acc[a][b2] = (f32x4){0.f, 0.f, 0.f, 0.f};

    const long bwave = (long)(waveN * 4) * 512 + lane * 8;

    #pragma unroll
    for (int cc = 0; cc < 8; ++cc) {
        const long aoffc = (long)cc * CC_STRIDE;
        const long boffc = (long)cc * 4096;
        for (int j = 0; j < 7; ++j) {
            const long aoffj = aoffc + (long)j * 64;            // wp += 2
            const long boffj = (long)(i * 7 + j) * 32768 + boffc;
            bf16x8 af[4], bfr[4];
            #pragma unroll
            for (int mt = 0; mt < 4; ++mt)
                af[mt] = *(const bf16x8*)(xps + abase[mt] + aoffj);
            #pragma unroll
            for (int nt = 0; nt < 4; ++nt)
                bfr[nt] = *(const bf16x8*)(wbs + boffj + (long)nt * 512 + bwave);
            #pragma unroll
            for (int mt = 0; mt < 4; ++mt)
                #pragma unroll
                for (int nt = 0; nt < 4; ++nt)
                    acc[mt][nt] = __builtin_amdgcn_mfma_f32_16x16x32_bf16(
                        af[mt], bfr[nt], acc[mt][nt], 0, 0, 0);
        }
    }

    #pragma unroll
    for (int mt = 0; mt < 4; ++mt) {
        int mrow = m0 + waveM * 64 + mt * 16 + quad * 4;
        #pragma unroll
        for (int nt = 0; nt < 4; ++nt) {
            int n = waveN * 64 + nt * 16 + l16;
            float* dst = kpart + ((long)i * M_TOT + mrow) * OC1 + n;
            #pragma unroll
            for (int r = 0; r < 4; ++r)
                dst[(long)r * OC1] = acc[mt][nt][r];
        }
    }
}

// conv2 + b2 + softmax, folding 7 kpart slices + b1 (validated R4).
__global__ __launch_bounds__(256) void attn_kernel3(const float* __restrict__ kpart,
                                                    const float* __restrict__ b1,
                                                    const float* __restrict__ W2,
                                                    const float* __restrict__ b2,
                                                    float* __restrict__ attn)
{
    __shared__ float ksum[128 * 33];     // [c][pix], pad 33
    __shared__ float sW2[128 * 49];      // [c][l]
    __shared__ float sredA[32 * 8];
    __shared__ float sredB[32 * 8];

    int tid  = threadIdx.x;
    int pix0 = blockIdx.x * 32;

    for (int idx = tid; idx < 128 * 49; idx += 256) {
        int c = idx / 49, l = idx - c * 49;
        sW2[idx] = W2[l * 128 + c];
    }

    int pix = tid >> 3, cg = tid & 7;
    {
        const float* kp = kpart + (size_t)(pix0 + pix) * OC1;
        #pragma unroll
        for (int q = 0; q < 4; ++q) {
            int c4 = cg * 16 + q * 4;
            float4 s = *(const float4*)(b1 + c4);
            #pragma unroll
            for (int sp = 0; sp < 7; ++sp) {
                float4 p = *(const float4*)(kp + (size_t)sp * M_TOT * OC1 + c4);
                s.x += p.x; s.y += p.y; s.z += p.z; s.w += p.w;
            }
            ksum[(c4 + 0) * 33 + pix] = s.x;
            ksum[(c4 + 1) * 33 + pix] = s.y;
            ksum[(c4 + 2) * 33 + pix] = s.z;
            ksum[(c4 + 3) * 33 + pix] = s.w;
        }
    }
    __syncthreads();

    int sub = tid & 7;
    float lg[7];
    int ntaps = 0;
    float lmax = -INFINITY;
    for (int l = sub; l < 49; l += 8) {
        float acc = b2[l];
        #pragma unroll 8
        for (int c = 0; c < 128; ++c)
            acc += ksum[c * 33 + pix] * sW2[c * 49 + l];
        lg[ntaps++] = acc;
        lmax = fmaxf(lmax, acc);
    }
    sredA[pix * 8 + sub] = lmax;
    __syncthreads();

    float m = sredA[pix * 8 + 0];
    #pragma unroll
    for (int t = 1; t < 8; ++t) m = fmaxf(m, sredA[pix * 8 + t]);
    float es = 0.f;
    for (int t = 0; t < ntaps; ++t) { lg[t] = __expf(lg[t] - m); es += lg[t]; }
    sredB[pix * 8 + sub] = es;
    __syncthreads();

    float S = 0.f;
    #pragma unroll
    for (int t = 0; t < 8; ++t) S += sredB[pix * 8 + t];
    float rinv = 1.0f / S;

    int pg = pix0 + pix;
    int b  = pg / HW_;
    int hw = pg - b * HW_;
    int t = 0;
    for (int l = sub; l < 49; l += 8, ++t)
        attn[((size_t)b * NT + l) * HW_ + hw] = lg[t] * rinv;
}

// out[b,c,h,w] = sum_ij attn[b,ij,h,w] * x[b,c,ih,iw]   (R5 rewrite)
// Block = (bh, 16-channel group), XCD-swizzled so each XCD owns 28 contiguous
// bh rows (x reuse across the 7 i-shifts stays in its L2). Zero-padded x rows
// sX[i][wp 68][c16] staged in LDS -> the 49-tap loop is mask-free; 49 attn
// weights in VGPRs; inner op = 1 ds_read_b128 (4 channels) + 4 FMA.
__global__ __launch_bounds__(256) void out_kernel3(const float* __restrict__ x,
                                                   const float* __restrict__ attn,
                                                   float* __restrict__ out)
{
    __shared__ float sX[7 * HP_ * 16];   // [i][wp][c] = 7616 floats, 30.5 KB
    __shared__ float sA[NT * 56];        // [tap][w], 11 KB

    int bid = blockIdx.x;                // < 3584
    int g   = bid & 7;                   // presumed XCD
    int s   = bid >> 3;                  // 0..447
    int bh  = g * 28 + (s % 28);         // 28 bh-rows per XCD slot
    int cg  = s / 28;                    // 0..15
    int b   = bh / H_;
    int h   = bh - b * H_;
    int c0  = cg * 16;
    int tid = threadIdx.x;

    // zero sX (covers invalid ih rows and the wp borders)
    for (int idx = tid; idx < 7 * HP_ * 16; idx += 256)
        sX[idx] = 0.0f;
    __syncthreads();

    // stage attn row
    for (int idx = tid; idx < NT * 56; idx += 256) {
        int l = idx / 56, w = idx - l * 56;
        sA[idx] = attn[((size_t)b * NT + l) * HW_ + h * W_ + w];
    }
    // stage valid x rows: thread = (c = tid>>4, wg = tid&15), w = wg + 16k
    {
        int c  = tid >> 4;
        int wg = tid & 15;
        const float* xc = x + (size_t)(b * C_ + c0 + c) * HW_;
        #pragma unroll
        for (int i = 0; i < 7; ++i) {
            int ih = h + 2 * i - 6;
            if (ih < 0 || ih >= H_) continue;
            const float* xr = xc + ih * W_;
            #pragma unroll
            for (int k = 0; k < 4; ++k) {
                int w = wg + 16 * k;
                if (w < W_)
                    sX[(i * HP_ + (w + 6)) * 16 + c] = xr[w];
            }
        }
    }
    __syncthreads();

    int lane = tid & 63;
    int wid  = tid >> 6;                 // wave -> channels c0+wid*4 .. +3
    int w    = lane;
    bool active = (w < W_);
    int wc = active ? w : (W_ - 1);

    float aR[NT];
    #pragma unroll
    for (int l = 0; l < NT; ++l)
        aR[l] = sA[l * 56 + wc];

    f32x4 acc = (f32x4){0.f, 0.f, 0.f, 0.f};
    #pragma unroll
    for (int i = 0; i < 7; ++i) {
        #pragma unroll
        for (int j = 0; j < 7; ++j) {
            // wp = (w + 2j - 6) + 6 = w + 2j  in [0,68): always valid
            f32x4 xv = *(const f32x4*)&sX[(i * HP_ + (wc + 2 * j)) * 16 + wid * 4];
            float a = aR[i * 7 + j];
            acc.x += a * xv.x; acc.y += a * xv.y;
            acc.z += a * xv.z; acc.w += a * xv.w;
        }
    }

    if (active) {
        size_t o = ((size_t)(b * C_ + c0 + wid * 4)) * HW_ + h * W_ + w;
        out[o + 0 * HW_] = acc.x;
        out[o + 1 * HW_] = acc.y;
        out[o + 2 * HW_] = acc.z;
        out[o + 3 * HW_] = acc.w;
    }
}

// ===========================================================================
// FALLBACK PATH (R1, proven): used only if ws_size < fast-path need
// ===========================================================================
__global__ __launch_bounds__(256) void wt_kernel(const float* __restrict__ W1,
                                                 float* __restrict__ wT)
{
    int idx = blockIdx.x * 256 + threadIdx.x;
    int oc = idx & 127;
    int ct = idx >> 7;
    wT[idx] = W1[oc * (C_ * NT) + ct];
}

__global__ __launch_bounds__(256) void conv1_kernel(const float* __restrict__ x,
                                                    const float* __restrict__ wT,
                                                    const float* __restrict__ b1,
                                                    float* __restrict__ k)
{
    int tid = threadIdx.x;
    int w   = tid & 63;
    int ty  = tid >> 6;
    int h   = blockIdx.x * 4 + ty;
    int oc0 = blockIdx.y * 8;
    int b   = blockIdx.z;

    const float* xb = x + (size_t)b * C_ * HW_;
    float acc[8] = {0.f,0.f,0.f,0.f,0.f,0.f,0.f,0.f};

    for (int i = 0; i < 7; ++i) {
        int ih = h + 2 * i - 6;
        if (ih < 0 || ih >= H_) continue;
        for (int j = 0; j < 7; ++j) {
            int iw = w + 2 * j - 6;
            bool v  = (iw >= 0) && (iw < W_);
            float m = v ? 1.0f : 0.0f;
            const float* xr = xb + ih * W_ + (v ? iw : 0);
            const float* wr = wT + (size_t)(i * 7 + j) * OC1 + oc0;
            #pragma unroll 4
            for (int c = 0; c < C_; ++c) {
                float xv = m * xr[(size_t)c * HW_];
                const float4 w0 = *(const float4*)(wr + (size_t)c * NT * OC1);
                const float4 w1 = *(const float4*)(wr + (size_t)c * NT * OC1 + 4);
                acc[0] += xv * w0.x; acc[1] += xv * w0.y;
                acc[2] += xv * w0.z; acc[3] += xv * w0.w;
                acc[4] += xv * w1.x; acc[5] += xv * w1.y;
                acc[6] += xv * w1.z; acc[7] += xv * w1.w;
            }
        }
    }
    if (w < W_) {
        size_t o = ((size_t)(b * OC1 + oc0)) * HW_ + h * W_ + w;
        #pragma unroll
        for (int q = 0; q < 8; ++q)
            k[o + (size_t)q * HW_] = acc[q] + b1[oc0 + q];
    }
}

__global__ __launch_bounds__(256) void attn_kernel(const float* __restrict__ kin,
                                                   const float* __restrict__ W2,
                                                   const float* __restrict__ b2,
                                                   float* __restrict__ attn)
{
    __shared__ float sW2[128 * 49];
    int tid = threadIdx.x;
    for (int idx = tid; idx < 128 * 49; idx += 256) {
        int c = idx / 49, l = idx - c * 49;
        sW2[idx] = W2[l * 128 + c];
    }
    __syncthreads();

    int wid  = tid >> 6;
    int lane = tid & 63;
    int pix  = blockIdx.x * 4 + wid;
    int b    = pix / HW_;
    int hw   = pix - b * HW_;
    int l    = (lane < 49) ? lane : 0;

    const float* kb = kin + (size_t)b * OC1 * HW_ + hw;
    float acc = b2[l];
    #pragma unroll 8
    for (int c = 0; c < 128; ++c)
        acc += kb[(size_t)c * HW_] * sW2[c * 49 + l];

    float logit = (lane < 49) ? acc : -INFINITY;
    float mx = logit;
    for (int s = 32; s > 0; s >>= 1) mx = fmaxf(mx, __shfl_xor(mx, s, 64));
    float e = (lane < 49) ? __expf(logit - mx) : 0.0f;
    float sum = e;
    for (int s = 32; s > 0; s >>= 1) sum += __shfl_xor(sum, s, 64);
    if (lane < 49)
        attn[((size_t)b * NT + lane) * HW_ + hw] = e / sum;
}

__global__ __launch_bounds__(256) void out_kernel(const float* __restrict__ x,
                                                  const float* __restrict__ attn,
                                                  float* __restrict__ out)
{
    int idx = blockIdx.x * 256 + threadIdx.x;
    int w  = idx % 56;
    int t  = idx / 56;
    int h  = t % 56;
    int t2 = t / 56;
    int c  = t2 & 255;
    int b  = t2 >> 8;

    const float* xb = x + (size_t)(b * C_ + c) * HW_;
    const float* ab = attn + (size_t)b * NT * HW_ + h * W_ + w;

    float acc = 0.f;
    #pragma unroll
    for (int i = 0; i < 7; ++i) {
        int ih = h + 2 * i - 6;
        bool hv = (ih >= 0) && (ih < H_);
        #pragma unroll
        for (int j = 0; j < 7; ++j) {
            int iw = w + 2 * j - 6;
            bool v  = hv && (iw >= 0) && (iw < W_);
            float m = v ? 1.0f : 0.0f;
            int off = v ? (ih * W_ + iw) : 0;
            acc += (m * xb[off]) * ab[(size_t)(i * 7 + j) * HW_];
        }
    }
    out[idx] = acc;
}

// ===========================================================================
extern "C" void kernel_launch(void* const* d_in, const int* in_sizes, int n_in,
                              void* d_out, int out_size, void* d_ws, size_t ws_size,
                              hipStream_t stream)
{
    const float* x  = (const float*)d_in[0];
    const float* W1 = (const float*)d_in[1];
    const float* b1 = (const float*)d_in[2];
    const float* W2 = (const float*)d_in[3];
    const float* b2 = (const float*)d_in[4];
    float* out = (float*)d_out;

    const size_t xp_b    = (size_t)B_ * HP_ * HP_ * 256 * 2;        //  9,469,952
    const size_t wtb_b   = (size_t)NT * 8 * 8 * 64 * 8 * 2;         //  3,211,264
    const size_t kpart_b = (size_t)7 * M_TOT * OC1 * 4;             // 44,957,696
    const size_t attn_b  = (size_t)B_ * NT * HW_ * 4;               //  2,458,624
    const size_t need = xp_b + wtb_b + kpart_b + attn_b;            // 60,097,536

    if (ws_size >= need) {
        char* base = (char*)d_ws;
        __hip_bfloat16* xp   = (__hip_bfloat16*)base;
        __hip_bfloat16* wTb2 = (__hip_bfloat16*)(base + xp_b);
        float* kpart = (float*)(base + xp_b + wtb_b);
        float* attn  = (float*)(base + xp_b + wtb_b + kpart_b);

        xpack2_kernel<<<2176, 256, 0, stream>>>(x, xp);
        wpack_kernel <<<6272, 256, 0, stream>>>(W1, wTb2);
        conv1_mfma2  <<<728, 256, 0, stream>>>(xp, wTb2, kpart);
        attn_kernel3 <<<392, 256, 0, stream>>>(kpart, b1, W2, b2, attn);
        out_kernel3  <<<3584, 256, 0, stream>>>(x, attn, out);
    } else {
        // R1 fallback (~14.6 MB)
        float* wT   = (float*)d_ws;
        float* kbuf = wT + 1605632;
        float* attn = kbuf + 1605632;
        wt_kernel   <<<6272, 256, 0, stream>>>(W1, wT);
        conv1_kernel<<<dim3(14, 16, 4), 256, 0, stream>>>(x, wT, b1, kbuf);
        attn_kernel <<<3136, 256, 0, stream>>>(kbuf, W2, b2, attn);
        out_kernel  <<<12544, 256, 0, stream>>>(x, attn, out);
    }
}